// Round 16
// baseline (137.788 us; speedup 1.0000x reference)
//
#include <hip/hip_runtime.h>
#include <hip/hip_bf16.h>

#define BB 4
#define TT 2048
#define DD 1024
#define HH 16

typedef __bf16 bf16;
typedef __bf16 bf16x8 __attribute__((ext_vector_type(8)));
typedef __bf16 bf16x4 __attribute__((ext_vector_type(4)));
typedef float f32x4 __attribute__((ext_vector_type(4)));
typedef float f32x16 __attribute__((ext_vector_type(16)));
typedef unsigned int u32;
typedef u32 u32x4 __attribute__((ext_vector_type(4)));

#define MFMA16(a, b, c) __builtin_amdgcn_mfma_f32_16x16x32_bf16(a, b, c, 0, 0, 0)
#define MFMA32(a, b, c) __builtin_amdgcn_mfma_f32_32x32x16_bf16(a, b, c, 0, 0, 0)

// softmax scale folded into Q at projection: (1/sqrt(64)) * log2(e)
#define C1 0.18033688011112042f

typedef __attribute__((address_space(1))) const u32 gau32;
typedef __attribute__((address_space(3))) u32 lau32;
static __device__ __forceinline__ void gload_lds16(const void* g, void* l) {
    __builtin_amdgcn_global_load_lds((gau32*)g, (lau32*)l, 16, 0, 0);
}

static __device__ __forceinline__ u32 cvtpk(float a, float b) {
    u32 r;
    asm("v_cvt_pk_bf16_f32 %0, %1, %2" : "=v"(r) : "v"(a), "v"(b));
    return r;
}

// raw v_exp_f32: args are bounded (|s*C1| < ~10); denormal handling unnecessary
static __device__ __forceinline__ float rexp2(float x) {
#if __has_builtin(__builtin_amdgcn_exp2f)
    return __builtin_amdgcn_exp2f(x);
#else
    float r;
    asm("v_exp_f32 %0, %1" : "=v"(r) : "v"(x));
    return r;
#endif
}

// ---------------- Kernel 0: all weights fp32 -> bf16 (Wout + Wq/Wk/Wv) ----------------
__global__ __launch_bounds__(256) void k_cvtall(const float* __restrict__ wo, const float* __restrict__ wq,
                                                const float* __restrict__ wk, const float* __restrict__ wv,
                                                bf16* __restrict__ ob, bf16* __restrict__ qb,
                                                bf16* __restrict__ kb, bf16* __restrict__ vb) {
    int i = (blockIdx.x * 256 + threadIdx.x) * 4;
    const float* s;
    bf16* d;
    int off;
    if (i < DD * DD) {
        s = wo; d = ob; off = i;
    } else {
        int j = i - DD * DD;
        int wsel = j >> 16;  // 65536 elements per projection weight
        off = j & 65535;
        s = wsel == 0 ? wq : (wsel == 1 ? wk : wv);
        d = wsel == 0 ? qb : (wsel == 1 ? kb : vb);
    }
    f32x4 v = *reinterpret_cast<const f32x4*>(s + off);
    bf16x4 r;
    r[0] = (bf16)v[0]; r[1] = (bf16)v[1]; r[2] = (bf16)v[2]; r[3] = (bf16)v[3];
    *reinterpret_cast<bf16x4*>(d + off) = r;
}

// ---------------- Kernel 1: QKV projection (bf16 weights, LDS-staged x) ----------------
__global__ __launch_bounds__(256) void k_qkv(const float* __restrict__ x,
                                             const bf16* __restrict__ Wq,
                                             const bf16* __restrict__ Wk,
                                             const bf16* __restrict__ Wv,
                                             bf16* __restrict__ Qb,
                                             bf16* __restrict__ Kb,
                                             bf16* __restrict__ VT) {
    __shared__ float xs[4][32 * 64];  // per-wave x tile (8 KB); reused as V-bounce scratch
    const int w = threadIdx.x >> 6, lane = threadIdx.x & 63;
    const int c = lane & 15, g = lane >> 4;
    const int bh = blockIdx.y;
    const int b = bh >> 4, h = bh & 15;
    const int tb = blockIdx.x * 128 + w * 32;

    float* xw = xs[w];
    {
        const int lr = lane >> 4;
        const int lch = lane & 15;
#pragma unroll
        for (int p = 0; p < 8; p++) {
            const int r = p * 4 + lr;
            const int ch = lch ^ (r & 15);
            gload_lds16(x + ((size_t)(b * TT + tb + r)) * DD + h * 64 + ch * 4,
                        (char*)xw + p * 1024);
        }
    }
    asm volatile("s_waitcnt vmcnt(0)" ::: "memory");

    bf16x8 a[2][2];
#pragma unroll
    for (int s = 0; s < 2; s++)
#pragma unroll
        for (int dt = 0; dt < 2; dt++) {
            const int r = 16 * s + c;
            const int c0 = 8 * dt + 2 * g;
            f32x4 lo = *reinterpret_cast<const f32x4*>(&xw[r * 64 + (c0 ^ (r & 15)) * 4]);
            f32x4 hi = *reinterpret_cast<const f32x4*>(&xw[r * 64 + ((c0 + 1) ^ (r & 15)) * 4]);
            u32x4 u;
            u[0] = cvtpk(lo[0], lo[1]);
            u[1] = cvtpk(lo[2], lo[3]);
            u[2] = cvtpk(hi[0], hi[1]);
            u[3] = cvtpk(hi[2], hi[3]);
            a[s][dt] = __builtin_bit_cast(bf16x8, u);
        }

    const bf16* const Ws[3] = {Wq, Wk, Wv};
    f32x4 acc[3][2][4];
#pragma unroll
    for (int m = 0; m < 3; m++)
#pragma unroll
        for (int s = 0; s < 2; s++)
#pragma unroll
            for (int e = 0; e < 4; e++)
#pragma unroll
                for (int r = 0; r < 4; r++) acc[m][s][e][r] = 0.0f;

#pragma unroll
    for (int m = 0; m < 3; m++) {
#pragma unroll
        for (int eg = 0; eg < 4; eg++) {
#pragma unroll
            for (int dt = 0; dt < 2; dt++) {
                bf16x8 bf = *reinterpret_cast<const bf16x8*>(
                    Ws[m] + (size_t)(h * 64 + 16 * eg + c) * 64 + 32 * dt + 8 * g);
#pragma unroll
                for (int s = 0; s < 2; s++)
                    acc[m][s][eg] = MFMA16(a[s][dt], bf, acc[m][s][eg]);  // proven: out[t][e]
            }
        }
    }

    bf16* const outs[2] = {Qb, Kb};
#pragma unroll
    for (int m = 0; m < 2; m++)
#pragma unroll
        for (int s = 0; s < 2; s++)
#pragma unroll
            for (int eg = 0; eg < 4; eg++)
#pragma unroll
                for (int r = 0; r < 4; r++) {
                    int t = tb + 16 * s + 4 * g + r;
                    float sv = acc[m][s][eg][r];
                    if (m == 0) sv *= C1;
                    outs[m][((size_t)bh * TT + t) * 64 + 16 * eg + c] = (bf16)sv;
                }

    // V: transpose via per-wave LDS tile [64 e][40 t_local], then pi-permuted store
    bf16* vl = (bf16*)xs[w];
#pragma unroll
    for (int s = 0; s < 2; s++)
#pragma unroll
        for (int eg = 0; eg < 4; eg++) {
            bf16x4 v4;
#pragma unroll
            for (int r = 0; r < 4; r++) v4[r] = (bf16)acc[2][s][eg][r];
            *reinterpret_cast<bf16x4*>(&vl[(16 * eg + c) * 40 + 16 * s + 4 * g]) = v4;
        }
#pragma unroll
    for (int n = 0; n < 8; n++) {
        const int np = (n & 4) | ((n & 1) << 1) | ((n >> 1) & 1);  // swap granule bits 0,1
        bf16x4 v = *reinterpret_cast<bf16x4*>(&vl[lane * 40 + 4 * n]);
        *reinterpret_cast<bf16x4*>(&VT[((size_t)bh * 64 + lane) * TT + tb + 4 * np]) = v;
    }
}

// ---------------- Kernel 2: flash attention (R15-proven counted-vmcnt pipeline) ----------------
#define ATTN_STEP(SKC, SVC, SKP, SVP, T, ISSUE, VM)                                             \
    do {                                                                                        \
        asm volatile("s_waitcnt vmcnt(" VM ")" ::: "memory");                                   \
        __builtin_amdgcn_s_barrier();                                                           \
        __builtin_amdgcn_sched_barrier(0);                                                      \
        if (ISSUE) {                                                                            \
            gload_lds16(kgsrc + (size_t)((T) + 2) * 4096, &(SKP)[w * 512]);                     \
            gload_lds16(vgsrc + (size_t)((T) + 2) * 64, &(SVP)[w * 512]);                       \
        }                                                                                       \
        f32x16 s0, s1;                                                                          \
        _Pragma("unroll") for (int i = 0; i < 16; i++) { s0[i] = 0.0f; s1[i] = 0.0f; }          \
        __builtin_amdgcn_s_setprio(1);                                                          \
        _Pragma("unroll") for (int d = 0; d < 4; d++) {                                         \
            bf16x8 ka0 = *reinterpret_cast<const bf16x8*>(&(SKC)[roff + d * 1024 + goff0]);     \
            bf16x8 ka1 = *reinterpret_cast<const bf16x8*>(&(SKC)[roff + d * 1024 + goff1]);     \
            s0 = MFMA32(ka0, aq[d], s0);                                                        \
            s1 = MFMA32(ka1, aq[d], s1);                                                        \
        }                                                                                       \
        __builtin_amdgcn_s_setprio(0);                                                          \
        u32 pk[2][4][2];                                                                        \
        _Pragma("unroll") for (int r = 0; r < 16; r++) { float p = rexp2(s0[r]); psum += p; s0[r] = p; } \
        _Pragma("unroll") for (int r = 0; r < 16; r++) { float p = rexp2(s1[r]); psum += p; s1[r] = p; } \
        _Pragma("unroll") for (int m = 0; m < 4; m++)                                           \
            _Pragma("unroll") for (int b2 = 0; b2 < 2; b2++) {                                  \
                pk[0][m][b2] = cvtpk(s0[4 * m + 2 * b2], s0[4 * m + 2 * b2 + 1]);               \
                pk[1][m][b2] = cvtpk(s1[4 * m + 2 * b2], s1[4 * m + 2 * b2 + 1]);               \
            }                                                                                   \
        __builtin_amdgcn_s_setprio(1);                                                          \
        _Pragma("unroll") for (int kt = 0; kt < 4; kt++) {                                      \
            u32x4 pu;                                                                           \
            pu[0] = pk[kt >> 1][2 * (kt & 1)][0];                                               \
            pu[1] = pk[kt >> 1][2 * (kt & 1)][1];                                               \
            pu[2] = pk[kt >> 1][2 * (kt & 1) + 1][0];                                           \
            pu[3] = pk[kt >> 1][2 * (kt & 1) + 1][1];                                           \
            bf16x8 pb = __builtin_bit_cast(bf16x8, pu);                                         \
            bf16x8 va0 = *reinterpret_cast<const bf16x8*>(&(SVC)[roff + kt * 1024 + goff0]);    \
            bf16x8 va1 = *reinterpret_cast<const bf16x8*>(&(SVC)[roff + kt * 1024 + goff1]);    \
            o0 = MFMA32(va0, pb, o0);                                                           \
            o1 = MFMA32(va1, pb, o1);                                                           \
        }                                                                                       \
        __builtin_amdgcn_s_setprio(0);                                                         \
    } while (0)

__global__ __launch_bounds__(512, 4) void k_attn(const bf16* __restrict__ Qb,
                                                 const bf16* __restrict__ Kb,
                                                 const bf16* __restrict__ VT,
                                                 bf16* __restrict__ AO) {
    __shared__ bf16 sK[3][64 * 64];
    __shared__ bf16 sV[3][64 * 64];
    const int w = threadIdx.x >> 6, lane = threadIdx.x & 63;
    const int q = lane & 31, h = lane >> 5;
    const int bid = blockIdx.x;
    const int swz = (bid & 7) * 64 + (bid >> 3);
    const int bh = swz >> 3;
    const int qb = (swz & 7) * 256 + w * 32;
    const bf16* Qh = Qb + (size_t)bh * TT * 64;
    const bf16* Kh = Kb + (size_t)bh * TT * 64;
    const bf16* Vh = VT + (size_t)bh * 64 * TT;

    const int gp = lane & 7;
    const int rp = w * 8 + (lane >> 3);
    const int u_ = rp & 15, J1 = rp >> 4;
    const int e_ = gp ^ (u_ & 7);
    const int st = 32 * (e_ >> 2) + 16 * (e_ & 1) + u_;
    const int sj = 2 * J1 + ((e_ >> 1) & 1);
    const bf16* kgsrc = Kh + (size_t)st * 64 + sj * 8;
    const bf16* vgsrc = Vh + (size_t)st * TT + sj * 8;

    gload_lds16(kgsrc, &sK[0][w * 512]);
    gload_lds16(vgsrc, &sV[0][w * 512]);
    gload_lds16(kgsrc + 4096, &sK[1][w * 512]);
    gload_lds16(vgsrc + 64, &sV[1][w * 512]);

    bf16x8 aq[4];
#pragma unroll
    for (int d = 0; d < 4; d++)
        aq[d] = *reinterpret_cast<const bf16x8*>(Qh + (size_t)(qb + q) * 64 + 16 * d + 8 * h);

    const int vv = 2 * h + ((q >> 4) & 1);
    const int gl = vv ^ (q & 3);
    const int gb2 = (q >> 2) & 1;
    const int roff = (q & 15) * 64;
    const int goff0 = (4 * gb2 + gl) * 8;
    const int goff1 = (4 * (1 ^ gb2) + gl) * 8;

    f32x16 o0, o1;
#pragma unroll
    for (int i = 0; i < 16; i++) { o0[i] = 0.0f; o1[i] = 0.0f; }
    float psum = 0.0f;

#pragma unroll 1
    for (int i = 0; i < 10; i++) {
        const int t0 = 3 * i;
        ATTN_STEP(sK[0], sV[0], sK[2], sV[2], t0, 1, "2");
        ATTN_STEP(sK[1], sV[1], sK[0], sV[0], t0 + 1, 1, "2");
        ATTN_STEP(sK[2], sV[2], sK[1], sV[1], t0 + 2, 1, "2");
    }
    ATTN_STEP(sK[0], sV[0], sK[2], sV[2], 30, 0, "2");
    ATTN_STEP(sK[1], sV[1], sK[0], sV[0], 31, 0, "0");

    const float l = psum + __shfl_xor(psum, 32);
    const float linv = 1.0f / l;

    const size_t obase = ((size_t)bh * TT + qb + q) * 64;
#pragma unroll
    for (int dg = 0; dg < 2; dg++)
#pragma unroll
        for (int m = 0; m < 4; m++) {
            bf16x4 v;
#pragma unroll
            for (int j = 0; j < 4; j++) {
                const float ov = dg ? o1[4 * m + j] : o0[4 * m + j];
                v[j] = (bf16)(ov * linv);
            }
            *reinterpret_cast<bf16x4*>(AO + obase + 32 * dg + 8 * m + 4 * h) = v;
        }
}

// ---------------- Kernel 3: output projection (counted-vmcnt 3-buffer GEMM) ----------------
// 512 blocks x 4 waves (2 blocks/CU). 128x128 tile, BK=32, 3 LDS buffers (48 KB),
// 2-step-deep prefetch with vmcnt(4) at top-of-step before a raw s_barrier (no drain).
// BK=32 fragment reads span a full contiguous 1 KB row-block -> conflict-free, no swizzle.
#define OSTAGE(BUF, KK)                                                                         \
    do {                                                                                        \
        const int h_ = (KK) >> 1, dc_ = ((KK) & 1) * 32;                                        \
        const bf16* Ab = AO + ((size_t)(b * HH + h_) * TT + t0) * 64 + dc_;                     \
        const bf16* Bb = Wo + (size_t)nb * DD + (KK) * 32;                                      \
        _Pragma("unroll") for (int p = 0; p < 2; p++) {                                         \
            const int r = (w * 2 + p) * 16 + (lane >> 2);                                       \
            const int ch = lane & 3;                                                            \
            gload_lds16(Ab + (size_t)r * 64 + ch * 8, &(sA[BUF])[(w * 2 + p) * 512]);           \
            gload_lds16(Bb + (size_t)r * DD + ch * 8, &(sB[BUF])[(w * 2 + p) * 512]);           \
        }                                                                                       \
    } while (0)

#define OSTEP(BUF, PBUF, KK, ISSUE, VM)                                                         \
    do {                                                                                        \
        asm volatile("s_waitcnt vmcnt(" VM ")" ::: "memory");                                   \
        __builtin_amdgcn_s_barrier();                                                           \
        __builtin_amdgcn_sched_barrier(0);                                                      \
        if (ISSUE) OSTAGE(PBUF, (KK) + 2);                                                      \
        const bf16* pa = sA[BUF];                                                               \
        const bf16* pb = sB[BUF];                                                               \
        bf16x8 aa[2];                                                                           \
        _Pragma("unroll") for (int s = 0; s < 2; s++)                                           \
            aa[s] = *reinterpret_cast<const bf16x8*>(&pa[(w * 32 + 16 * s + c) * 32 + 8 * g]);  \
        __builtin_amdgcn_s_setprio(1);                                                          \
        _Pragma("unroll") for (int ng = 0; ng < 8; ng++) {                                      \
            bf16x8 bb = *reinterpret_cast<const bf16x8*>(&pb[(16 * ng + c) * 32 + 8 * g]);      \
            _Pragma("unroll") for (int s = 0; s < 2; s++)                                       \
                acc[s][ng] = MFMA16(aa[s], bb, acc[s][ng]);                                     \
        }                                                                                       \
        __builtin_amdgcn_s_setprio(0);                                                          \
    } while (0)

__global__ __launch_bounds__(256, 2) void k_oproj(const bf16* __restrict__ AO,
                                                  const bf16* __restrict__ Wo,
                                                  float* __restrict__ out) {
    __shared__ bf16 sA[3][128 * 32];
    __shared__ bf16 sB[3][128 * 32];
    const int w = threadIdx.x >> 6, lane = threadIdx.x & 63;
    const int c = lane & 15, g = lane >> 4;
    const int bid = blockIdx.x;
    const int nb = (bid & 7) * 128;          // XCD-swizzled: each XCD owns one Wo slab
    const int row0 = (bid >> 3) * 128;       // 0..8191 in (B*T) space
    const int b = row0 >> 11;
    const int t0 = row0 & 2047;

    f32x4 acc[2][8];
#pragma unroll
    for (int s = 0; s < 2; s++)
#pragma unroll
        for (int ng = 0; ng < 8; ng++)
#pragma unroll
            for (int r = 0; r < 4; r++) acc[s][ng][r] = 0.0f;

    // prologue: stage k-step 0 -> buf0, 1 -> buf1
    OSTAGE(0, 0);
    OSTAGE(1, 1);

    // main loop: steps 0..29 (3-buffer rotation), epilogue steps 30, 31
#pragma unroll 1
    for (int i = 0; i < 10; i++) {
        const int k0 = 3 * i;
        OSTEP(0, 2, k0, 1, "4");
        OSTEP(1, 0, k0 + 1, 1, "4");
        OSTEP(2, 1, k0 + 2, 1, "4");
    }
    OSTEP(0, 2, 30, 0, "4");
    OSTEP(1, 0, 31, 0, "0");

    const int mb = row0 + w * 32;
#pragma unroll
    for (int s = 0; s < 2; s++)
#pragma unroll
        for (int ng = 0; ng < 8; ng++)
#pragma unroll
            for (int r = 0; r < 4; r++)
                out[(size_t)(mb + 16 * s + 4 * g + r) * DD + nb + 16 * ng + c] = acc[s][ng][r];
}

extern "C" void kernel_launch(void* const* d_in, const int* in_sizes, int n_in,
                              void* d_out, int out_size, void* d_ws, size_t ws_size,
                              hipStream_t stream) {
    const float* x = (const float*)d_in[0];
    const float* Wq = (const float*)d_in[1];
    const float* Wk = (const float*)d_in[2];
    const float* Wv = (const float*)d_in[3];
    const float* Wo = (const float*)d_in[4];
    float* out = (float*)d_out;

    char* ws = (char*)d_ws;
    bf16* Qb = (bf16*)(ws);                                   // 16 MiB
    bf16* Kb = (bf16*)(ws + (16ll << 20));                    // 16 MiB
    bf16* VT = (bf16*)(ws + (32ll << 20));                    // 16 MiB
    bf16* AO = (bf16*)(ws + (48ll << 20));                    // 16 MiB
    bf16* Wob = (bf16*)(ws + (64ll << 20));                   // 2 MiB
    bf16* Wqb = (bf16*)(ws + (66ll << 20));                   // 128 KiB
    bf16* Wkb = (bf16*)(ws + (66ll << 20) + (128ll << 10));   // 128 KiB
    bf16* Wvb = (bf16*)(ws + (66ll << 20) + (256ll << 10));   // 128 KiB

    k_cvtall<<<1216, 256, 0, stream>>>(Wo, Wq, Wk, Wv, Wob, Wqb, Wkb, Wvb);
    k_qkv<<<dim3(TT / 128, BB * HH), 256, 0, stream>>>(x, Wqb, Wkb, Wvb, Qb, Kb, VT);
    k_attn<<<512, 512, 0, stream>>>(Qb, Kb, VT, AO);
    k_oproj<<<512, 256, 0, stream>>>(AO, Wob, out);
}

// Round 17
// 133.691 us; speedup vs baseline: 1.0306x; 1.0306x over previous
//
#include <hip/hip_runtime.h>
#include <hip/hip_bf16.h>

#define BB 4
#define TT 2048
#define DD 1024
#define HH 16

typedef __bf16 bf16;
typedef __bf16 bf16x8 __attribute__((ext_vector_type(8)));
typedef __bf16 bf16x4 __attribute__((ext_vector_type(4)));
typedef float f32x4 __attribute__((ext_vector_type(4)));
typedef float f32x16 __attribute__((ext_vector_type(16)));
typedef unsigned int u32;
typedef u32 u32x4 __attribute__((ext_vector_type(4)));

#define MFMA16(a, b, c) __builtin_amdgcn_mfma_f32_16x16x32_bf16(a, b, c, 0, 0, 0)
#define MFMA32(a, b, c) __builtin_amdgcn_mfma_f32_32x32x16_bf16(a, b, c, 0, 0, 0)

// softmax scale folded into Q at projection: (1/sqrt(64)) * log2(e)
#define C1 0.18033688011112042f

typedef __attribute__((address_space(1))) const u32 gau32;
typedef __attribute__((address_space(3))) u32 lau32;
static __device__ __forceinline__ void gload_lds16(const void* g, void* l) {
    __builtin_amdgcn_global_load_lds((gau32*)g, (lau32*)l, 16, 0, 0);
}

static __device__ __forceinline__ u32 cvtpk(float a, float b) {
    u32 r;
    asm("v_cvt_pk_bf16_f32 %0, %1, %2" : "=v"(r) : "v"(a), "v"(b));
    return r;
}

// raw v_exp_f32: args are bounded (|s*C1| < ~10); denormal handling unnecessary
static __device__ __forceinline__ float rexp2(float x) {
#if __has_builtin(__builtin_amdgcn_exp2f)
    return __builtin_amdgcn_exp2f(x);
#else
    float r;
    asm("v_exp_f32 %0, %1" : "=v"(r) : "v"(x));
    return r;
#endif
}

// ---------------- Kernel 0: all weights fp32 -> bf16 (Wout + Wq/Wk/Wv) ----------------
__global__ __launch_bounds__(256) void k_cvtall(const float* __restrict__ wo, const float* __restrict__ wq,
                                                const float* __restrict__ wk, const float* __restrict__ wv,
                                                bf16* __restrict__ ob, bf16* __restrict__ qb,
                                                bf16* __restrict__ kb, bf16* __restrict__ vb) {
    int i = (blockIdx.x * 256 + threadIdx.x) * 4;
    const float* s;
    bf16* d;
    int off;
    if (i < DD * DD) {
        s = wo; d = ob; off = i;
    } else {
        int j = i - DD * DD;
        int wsel = j >> 16;  // 65536 elements per projection weight
        off = j & 65535;
        s = wsel == 0 ? wq : (wsel == 1 ? wk : wv);
        d = wsel == 0 ? qb : (wsel == 1 ? kb : vb);
    }
    f32x4 v = *reinterpret_cast<const f32x4*>(s + off);
    bf16x4 r;
    r[0] = (bf16)v[0]; r[1] = (bf16)v[1]; r[2] = (bf16)v[2]; r[3] = (bf16)v[3];
    *reinterpret_cast<bf16x4*>(d + off) = r;
}

// ---------------- Kernel 1: QKV projection (bf16 weights, LDS-staged x) ----------------
__global__ __launch_bounds__(256) void k_qkv(const float* __restrict__ x,
                                             const bf16* __restrict__ Wq,
                                             const bf16* __restrict__ Wk,
                                             const bf16* __restrict__ Wv,
                                             bf16* __restrict__ Qb,
                                             bf16* __restrict__ Kb,
                                             bf16* __restrict__ VT) {
    __shared__ float xs[4][32 * 64];  // per-wave x tile (8 KB); reused as V-bounce scratch
    const int w = threadIdx.x >> 6, lane = threadIdx.x & 63;
    const int c = lane & 15, g = lane >> 4;
    const int bh = blockIdx.y;
    const int b = bh >> 4, h = bh & 15;
    const int tb = blockIdx.x * 128 + w * 32;

    float* xw = xs[w];
    {
        const int lr = lane >> 4;
        const int lch = lane & 15;
#pragma unroll
        for (int p = 0; p < 8; p++) {
            const int r = p * 4 + lr;
            const int ch = lch ^ (r & 15);
            gload_lds16(x + ((size_t)(b * TT + tb + r)) * DD + h * 64 + ch * 4,
                        (char*)xw + p * 1024);
        }
    }
    asm volatile("s_waitcnt vmcnt(0)" ::: "memory");

    bf16x8 a[2][2];
#pragma unroll
    for (int s = 0; s < 2; s++)
#pragma unroll
        for (int dt = 0; dt < 2; dt++) {
            const int r = 16 * s + c;
            const int c0 = 8 * dt + 2 * g;
            f32x4 lo = *reinterpret_cast<const f32x4*>(&xw[r * 64 + (c0 ^ (r & 15)) * 4]);
            f32x4 hi = *reinterpret_cast<const f32x4*>(&xw[r * 64 + ((c0 + 1) ^ (r & 15)) * 4]);
            u32x4 u;
            u[0] = cvtpk(lo[0], lo[1]);
            u[1] = cvtpk(lo[2], lo[3]);
            u[2] = cvtpk(hi[0], hi[1]);
            u[3] = cvtpk(hi[2], hi[3]);
            a[s][dt] = __builtin_bit_cast(bf16x8, u);
        }

    const bf16* const Ws[3] = {Wq, Wk, Wv};
    f32x4 acc[3][2][4];
#pragma unroll
    for (int m = 0; m < 3; m++)
#pragma unroll
        for (int s = 0; s < 2; s++)
#pragma unroll
            for (int e = 0; e < 4; e++)
#pragma unroll
                for (int r = 0; r < 4; r++) acc[m][s][e][r] = 0.0f;

#pragma unroll
    for (int m = 0; m < 3; m++) {
#pragma unroll
        for (int eg = 0; eg < 4; eg++) {
#pragma unroll
            for (int dt = 0; dt < 2; dt++) {
                bf16x8 bf = *reinterpret_cast<const bf16x8*>(
                    Ws[m] + (size_t)(h * 64 + 16 * eg + c) * 64 + 32 * dt + 8 * g);
#pragma unroll
                for (int s = 0; s < 2; s++)
                    acc[m][s][eg] = MFMA16(a[s][dt], bf, acc[m][s][eg]);  // proven: out[t][e]
            }
        }
    }

    bf16* const outs[2] = {Qb, Kb};
#pragma unroll
    for (int m = 0; m < 2; m++)
#pragma unroll
        for (int s = 0; s < 2; s++)
#pragma unroll
            for (int eg = 0; eg < 4; eg++)
#pragma unroll
                for (int r = 0; r < 4; r++) {
                    int t = tb + 16 * s + 4 * g + r;
                    float sv = acc[m][s][eg][r];
                    if (m == 0) sv *= C1;
                    outs[m][((size_t)bh * TT + t) * 64 + 16 * eg + c] = (bf16)sv;
                }

    // V: transpose via per-wave LDS tile [64 e][40 t_local], then pi-permuted store
    bf16* vl = (bf16*)xs[w];
#pragma unroll
    for (int s = 0; s < 2; s++)
#pragma unroll
        for (int eg = 0; eg < 4; eg++) {
            bf16x4 v4;
#pragma unroll
            for (int r = 0; r < 4; r++) v4[r] = (bf16)acc[2][s][eg][r];
            *reinterpret_cast<bf16x4*>(&vl[(16 * eg + c) * 40 + 16 * s + 4 * g]) = v4;
        }
#pragma unroll
    for (int n = 0; n < 8; n++) {
        const int np = (n & 4) | ((n & 1) << 1) | ((n >> 1) & 1);  // swap granule bits 0,1
        bf16x4 v = *reinterpret_cast<bf16x4*>(&vl[lane * 40 + 4 * n]);
        *reinterpret_cast<bf16x4*>(&VT[((size_t)bh * 64 + lane) * TT + tb + 4 * np]) = v;
    }
}

// ---------------- Kernel 2: flash attention (R15-proven counted-vmcnt pipeline) ----------------
#define ATTN_STEP(SKC, SVC, SKP, SVP, T, ISSUE, VM)                                             \
    do {                                                                                        \
        asm volatile("s_waitcnt vmcnt(" VM ")" ::: "memory");                                   \
        __builtin_amdgcn_s_barrier();                                                           \
        __builtin_amdgcn_sched_barrier(0);                                                      \
        if (ISSUE) {                                                                            \
            gload_lds16(kgsrc + (size_t)((T) + 2) * 4096, &(SKP)[w * 512]);                     \
            gload_lds16(vgsrc + (size_t)((T) + 2) * 64, &(SVP)[w * 512]);                       \
        }                                                                                       \
        f32x16 s0, s1;                                                                          \
        _Pragma("unroll") for (int i = 0; i < 16; i++) { s0[i] = 0.0f; s1[i] = 0.0f; }          \
        __builtin_amdgcn_s_setprio(1);                                                          \
        _Pragma("unroll") for (int d = 0; d < 4; d++) {                                         \
            bf16x8 ka0 = *reinterpret_cast<const bf16x8*>(&(SKC)[roff + d * 1024 + goff0]);     \
            bf16x8 ka1 = *reinterpret_cast<const bf16x8*>(&(SKC)[roff + d * 1024 + goff1]);     \
            s0 = MFMA32(ka0, aq[d], s0);                                                        \
            s1 = MFMA32(ka1, aq[d], s1);                                                        \
        }                                                                                       \
        __builtin_amdgcn_s_setprio(0);                                                          \
        u32 pk[2][4][2];                                                                        \
        _Pragma("unroll") for (int r = 0; r < 16; r++) { float p = rexp2(s0[r]); psum += p; s0[r] = p; } \
        _Pragma("unroll") for (int r = 0; r < 16; r++) { float p = rexp2(s1[r]); psum += p; s1[r] = p; } \
        _Pragma("unroll") for (int m = 0; m < 4; m++)                                           \
            _Pragma("unroll") for (int b2 = 0; b2 < 2; b2++) {                                  \
                pk[0][m][b2] = cvtpk(s0[4 * m + 2 * b2], s0[4 * m + 2 * b2 + 1]);               \
                pk[1][m][b2] = cvtpk(s1[4 * m + 2 * b2], s1[4 * m + 2 * b2 + 1]);               \
            }                                                                                   \
        __builtin_amdgcn_s_setprio(1);                                                          \
        _Pragma("unroll") for (int kt = 0; kt < 4; kt++) {                                      \
            u32x4 pu;                                                                           \
            pu[0] = pk[kt >> 1][2 * (kt & 1)][0];                                               \
            pu[1] = pk[kt >> 1][2 * (kt & 1)][1];                                               \
            pu[2] = pk[kt >> 1][2 * (kt & 1) + 1][0];                                           \
            pu[3] = pk[kt >> 1][2 * (kt & 1) + 1][1];                                           \
            bf16x8 pb = __builtin_bit_cast(bf16x8, pu);                                         \
            bf16x8 va0 = *reinterpret_cast<const bf16x8*>(&(SVC)[roff + kt * 1024 + goff0]);    \
            bf16x8 va1 = *reinterpret_cast<const bf16x8*>(&(SVC)[roff + kt * 1024 + goff1]);    \
            o0 = MFMA32(va0, pb, o0);                                                           \
            o1 = MFMA32(va1, pb, o1);                                                           \
        }                                                                                       \
        __builtin_amdgcn_s_setprio(0);                                                         \
    } while (0)

__global__ __launch_bounds__(512, 4) void k_attn(const bf16* __restrict__ Qb,
                                                 const bf16* __restrict__ Kb,
                                                 const bf16* __restrict__ VT,
                                                 bf16* __restrict__ AO) {
    __shared__ bf16 sK[3][64 * 64];
    __shared__ bf16 sV[3][64 * 64];
    const int w = threadIdx.x >> 6, lane = threadIdx.x & 63;
    const int q = lane & 31, h = lane >> 5;
    const int bid = blockIdx.x;
    const int swz = (bid & 7) * 64 + (bid >> 3);
    const int bh = swz >> 3;
    const int qb = (swz & 7) * 256 + w * 32;
    const bf16* Qh = Qb + (size_t)bh * TT * 64;
    const bf16* Kh = Kb + (size_t)bh * TT * 64;
    const bf16* Vh = VT + (size_t)bh * 64 * TT;

    const int gp = lane & 7;
    const int rp = w * 8 + (lane >> 3);
    const int u_ = rp & 15, J1 = rp >> 4;
    const int e_ = gp ^ (u_ & 7);
    const int st = 32 * (e_ >> 2) + 16 * (e_ & 1) + u_;
    const int sj = 2 * J1 + ((e_ >> 1) & 1);
    const bf16* kgsrc = Kh + (size_t)st * 64 + sj * 8;
    const bf16* vgsrc = Vh + (size_t)st * TT + sj * 8;

    gload_lds16(kgsrc, &sK[0][w * 512]);
    gload_lds16(vgsrc, &sV[0][w * 512]);
    gload_lds16(kgsrc + 4096, &sK[1][w * 512]);
    gload_lds16(vgsrc + 64, &sV[1][w * 512]);

    bf16x8 aq[4];
#pragma unroll
    for (int d = 0; d < 4; d++)
        aq[d] = *reinterpret_cast<const bf16x8*>(Qh + (size_t)(qb + q) * 64 + 16 * d + 8 * h);

    const int vv = 2 * h + ((q >> 4) & 1);
    const int gl = vv ^ (q & 3);
    const int gb2 = (q >> 2) & 1;
    const int roff = (q & 15) * 64;
    const int goff0 = (4 * gb2 + gl) * 8;
    const int goff1 = (4 * (1 ^ gb2) + gl) * 8;

    f32x16 o0, o1;
#pragma unroll
    for (int i = 0; i < 16; i++) { o0[i] = 0.0f; o1[i] = 0.0f; }
    float psum = 0.0f;

#pragma unroll 1
    for (int i = 0; i < 10; i++) {
        const int t0 = 3 * i;
        ATTN_STEP(sK[0], sV[0], sK[2], sV[2], t0, 1, "2");
        ATTN_STEP(sK[1], sV[1], sK[0], sV[0], t0 + 1, 1, "2");
        ATTN_STEP(sK[2], sV[2], sK[1], sV[1], t0 + 2, 1, "2");
    }
    ATTN_STEP(sK[0], sV[0], sK[2], sV[2], 30, 0, "2");
    ATTN_STEP(sK[1], sV[1], sK[0], sV[0], 31, 0, "0");

    const float l = psum + __shfl_xor(psum, 32);
    const float linv = 1.0f / l;

    const size_t obase = ((size_t)bh * TT + qb + q) * 64;
#pragma unroll
    for (int dg = 0; dg < 2; dg++)
#pragma unroll
        for (int m = 0; m < 4; m++) {
            bf16x4 v;
#pragma unroll
            for (int j = 0; j < 4; j++) {
                const float ov = dg ? o1[4 * m + j] : o0[4 * m + j];
                v[j] = (bf16)(ov * linv);
            }
            *reinterpret_cast<bf16x4*>(AO + obase + 32 * dg + 8 * m + 4 * h) = v;
        }
}

// ---------------- Kernel 3: output projection (R15-proven LDS-staged GEMM, BK=64) ----------------
#define OSTAGE(BUF, H)                                                                          \
    do {                                                                                        \
        const bf16* Ab = AO + ((size_t)(b * HH + (H)) * TT + t0) * 64;                          \
        const bf16* Bb = Wo + (size_t)nb * DD + (H) * 64;                                       \
        _Pragma("unroll") for (int p = 0; p < 4; p++) {                                         \
            const int r = p * 32 + w * 8 + (lane >> 3);                                         \
            const int jj = (lane & 7) ^ (r & 7);                                                \
            gload_lds16(Ab + (size_t)r * 64 + jj * 8, &sA[BUF][p * 2048 + w * 512]);            \
            gload_lds16(Bb + (size_t)r * DD + jj * 8, &sB[BUF][p * 2048 + w * 512]);            \
        }                                                                                       \
    } while (0)

__global__ __launch_bounds__(256, 2) void k_oproj(const bf16* __restrict__ AO,
                                                  const bf16* __restrict__ Wo,
                                                  float* __restrict__ out) {
    __shared__ bf16 sA[2][128 * 64];
    __shared__ bf16 sB[2][128 * 64];
    const int w = threadIdx.x >> 6, lane = threadIdx.x & 63;
    const int c = lane & 15, g = lane >> 4;
    const int bid = blockIdx.x;
    const int nb = (bid & 7) * 128;          // XCD-swizzled: each XCD owns one Wo slab
    const int row0 = (bid >> 3) * 128;       // 0..8191 in (B*T) space
    const int b = row0 >> 11;
    const int t0 = row0 & 2047;

    f32x4 acc[2][8];
#pragma unroll
    for (int s = 0; s < 2; s++)
#pragma unroll
        for (int ng = 0; ng < 8; ng++)
#pragma unroll
            for (int r = 0; r < 4; r++) acc[s][ng][r] = 0.0f;

    OSTAGE(0, 0);
    __syncthreads();

    int buf = 0;
#pragma unroll 1
    for (int hh = 0; hh < 16; hh++) {
        if (hh < 15) OSTAGE(buf ^ 1, hh + 1);
        const bf16* pa = sA[buf];
        const bf16* pb = sB[buf];
#pragma unroll
        for (int dt = 0; dt < 2; dt++) {
            const int gsw = ((4 * dt + g) ^ (c & 7)) * 8;
            bf16x8 aa[2];
#pragma unroll
            for (int s = 0; s < 2; s++)
                aa[s] = *reinterpret_cast<const bf16x8*>(&pa[(w * 32 + 16 * s + c) * 64 + gsw]);
            __builtin_amdgcn_s_setprio(1);
#pragma unroll
            for (int ng = 0; ng < 8; ng++) {
                bf16x8 bb = *reinterpret_cast<const bf16x8*>(&pb[(16 * ng + c) * 64 + gsw]);
#pragma unroll
                for (int s = 0; s < 2; s++)
                    acc[s][ng] = MFMA16(aa[s], bb, acc[s][ng]);
            }
            __builtin_amdgcn_s_setprio(0);
        }
        __syncthreads();
        buf ^= 1;
    }

    const int mb = row0 + w * 32;
#pragma unroll
    for (int s = 0; s < 2; s++)
#pragma unroll
        for (int ng = 0; ng < 8; ng++)
#pragma unroll
            for (int r = 0; r < 4; r++)
                out[(size_t)(mb + 16 * s + 4 * g + r) * DD + nb + 16 * ng + c] = acc[s][ng][r];
}

extern "C" void kernel_launch(void* const* d_in, const int* in_sizes, int n_in,
                              void* d_out, int out_size, void* d_ws, size_t ws_size,
                              hipStream_t stream) {
    const float* x = (const float*)d_in[0];
    const float* Wq = (const float*)d_in[1];
    const float* Wk = (const float*)d_in[2];
    const float* Wv = (const float*)d_in[3];
    const float* Wo = (const float*)d_in[4];
    float* out = (float*)d_out;

    char* ws = (char*)d_ws;
    bf16* Qb = (bf16*)(ws);                                   // 16 MiB
    bf16* Kb = (bf16*)(ws + (16ll << 20));                    // 16 MiB
    bf16* VT = (bf16*)(ws + (32ll << 20));                    // 16 MiB
    bf16* AO = (bf16*)(ws + (48ll << 20));                    // 16 MiB
    bf16* Wob = (bf16*)(ws + (64ll << 20));                   // 2 MiB
    bf16* Wqb = (bf16*)(ws + (66ll << 20));                   // 128 KiB
    bf16* Wkb = (bf16*)(ws + (66ll << 20) + (128ll << 10));   // 128 KiB
    bf16* Wvb = (bf16*)(ws + (66ll << 20) + (256ll << 10));   // 128 KiB

    k_cvtall<<<1216, 256, 0, stream>>>(Wo, Wq, Wk, Wv, Wob, Wqb, Wkb, Wvb);
    k_qkv<<<dim3(TT / 128, BB * HH), 256, 0, stream>>>(x, Wqb, Wkb, Wvb, Qb, Kb, VT);
    k_attn<<<512, 512, 0, stream>>>(Qb, Kb, VT, AO);
    k_oproj<<<512, 256, 0, stream>>>(AO, Wob, out);
}